// Round 1
// baseline (118.694 us; speedup 1.0000x reference)
//
#include <hip/hip_runtime.h>

#define GAMMA 0.999f
#define LAMBD 0.7f
#define ALPHA 0.99f

constexpr int A_DIM = 64;
constexpr int CH    = 128;   // scan chunk length (T/CH = 2048 chunks)

// ---------------------------------------------------------------------------
// K1: one wave (64 lanes) per timestep row. Computes v_t, v_tp1 (wave reduce),
// gathers q_t_a / pi_t_a / mu_a via shuffle, writes advantages and the scan
// coefficients {E, k, A, Bp} per element:
//   targets[t] = E_t + k_t * y_{t+1}
//   y_t        = A_t + Bp_t * y_{t+1},   y_T = 0
// ---------------------------------------------------------------------------
__global__ void k_row(const float* __restrict__ q,
                      const float* __restrict__ q_tar,
                      const float* __restrict__ pi,
                      const int*   __restrict__ a_t,
                      const float* __restrict__ r_t,
                      const float* __restrict__ mu_t,
                      const int*   __restrict__ done_t,
                      float*  __restrict__ adv_out,   // T*A floats
                      float4* __restrict__ scr,       // T entries {E,k,A,Bp}
                      int T)
{
    int wave = (blockIdx.x * blockDim.x + threadIdx.x) >> 6;
    int lane = threadIdx.x & 63;
    if (wave >= T) return;
    const int r = wave;
    const int base = r * A_DIM + lane;

    float pi_t = pi[base];
    float q_tv = q[base];
    float pi_p = pi[base + A_DIM];
    float q_p  = q_tar[base + A_DIM];
    float mu   = mu_t[base];

    float s0 = pi_t * q_tv;   // -> v_t
    float s1 = pi_p * q_p;    // -> v_tp1
    #pragma unroll
    for (int off = 32; off; off >>= 1) {
        s0 += __shfl_xor(s0, off);
        s1 += __shfl_xor(s1, off);
    }

    int   a      = a_t[r];
    float q_t_a  = __shfl(q_tv, a);
    float pi_t_a = __shfl(pi_t, a);
    float mu_a   = __shfl(mu,   a);

    float done_f = (float)done_t[r];
    float kmask  = 1.0f - done_f;

    float est = r_t[r] + kmask * (GAMMA * s1);
    float td  = est - q_t_a;
    float rho = pi_t_a / mu_a;
    float c   = LAMBD * fminf(fmaxf(rho, 0.0f), 1.0f);

    float Acoef = (LAMBD * GAMMA) * rho * td;
    float Bp    = kmask * (GAMMA * c);
    float E     = est + ALPHA * (q_t_a - s0);

    adv_out[base] = (1.0f - ALPHA) * (q_tv - s0);
    if (lane == 0) scr[r] = make_float4(E, kmask, Acoef, Bp);
}

// ---------------------------------------------------------------------------
// K2a: per-chunk affine composition (right-to-left):  y_s = Aacc + Bacc * y_e
// ---------------------------------------------------------------------------
__global__ void k_chunk(const float4* __restrict__ scr,
                        float2* __restrict__ cab, int T)
{
    int c = blockIdx.x * blockDim.x + threadIdx.x;
    int nch = T / CH;
    if (c >= nch) return;
    float Aacc = 0.0f, Bacc = 1.0f;
    int base = c * CH;
    for (int j = CH - 1; j >= 0; --j) {
        float4 v = scr[base + j];
        Aacc = v.z + v.w * Aacc;
        Bacc = v.w * Bacc;
    }
    cab[c] = make_float2(Aacc, Bacc);
}

// ---------------------------------------------------------------------------
// K2b: single-block (1024 threads) suffix scan over 2048 chunk pairs.
// Writes ybound[c] = y at element index c*CH  (ybound[nch] = 0).
// ---------------------------------------------------------------------------
__global__ void k_scan(const float2* __restrict__ cab,
                       float* __restrict__ ybound, int nch)
{
    __shared__ float sA[1024], sB[1024];
    int i = threadIdx.x;                 // handles chunks 2i, 2i+1
    float2 p0 = cab[2 * i];
    float2 p1 = cab[2 * i + 1];
    float Ai = p0.x + p0.y * p1.x;       // comp(p0, p1)
    float Bi = p0.y * p1.y;
    sA[i] = Ai; sB[i] = Bi;
    __syncthreads();
    for (int off = 1; off < 1024; off <<= 1) {
        float An = 0.0f, Bn = 1.0f;
        if (i + off < 1024) { An = sA[i + off]; Bn = sB[i + off]; }
        __syncthreads();
        Ai = Ai + Bi * An;
        Bi = Bi * Bn;
        sA[i] = Ai; sB[i] = Bi;
        __syncthreads();
    }
    // S_i = comp over super-chunks i..1023; y at boundary 2i = S_i.A
    ybound[2 * i] = Ai;
    float yNext = (i + 1 < 1024) ? sA[i + 1] : 0.0f;
    ybound[2 * i + 1] = p1.x + p1.y * yNext;
    if (i == 0) ybound[nch] = 0.0f;
}

// ---------------------------------------------------------------------------
// K2c: per-chunk expansion writing targets_q.
// ---------------------------------------------------------------------------
__global__ void k_final(const float4* __restrict__ scr,
                        const float* __restrict__ ybound,
                        float* __restrict__ targets, int T)
{
    int c = blockIdx.x * blockDim.x + threadIdx.x;
    int nch = T / CH;
    if (c >= nch) return;
    float y = ybound[c + 1];
    int base = c * CH;
    for (int j = CH - 1; j >= 0; --j) {
        float4 v = scr[base + j];
        targets[base + j] = v.x + v.y * y;
        y = v.z + v.w * y;
    }
}

extern "C" void kernel_launch(void* const* d_in, const int* in_sizes, int n_in,
                              void* d_out, int out_size, void* d_ws, size_t ws_size,
                              hipStream_t stream) {
    const float* q     = (const float*)d_in[0];
    const float* q_tar = (const float*)d_in[1];
    const float* pi    = (const float*)d_in[2];
    const int*   a_t   = (const int*)  d_in[3];
    const float* r_t   = (const float*)d_in[4];
    const float* mu_t  = (const float*)d_in[5];
    const int*   done_t= (const int*)  d_in[6];

    const int T = in_sizes[3];           // 262144
    const int nch = T / CH;              // 2048

    float* targets = (float*)d_out;          // T floats
    float* adv     = (float*)d_out + T;      // T*A floats

    float4* scr    = (float4*)d_ws;                                   // 16*T bytes
    float2* cab    = (float2*)((char*)d_ws + (size_t)16 * T);         // 8*nch
    float*  ybound = (float*)((char*)d_ws + (size_t)16 * T + (size_t)8 * nch);

    // K1: one wave per row
    {
        int threads = 256;
        int blocks  = (T * 64) / threads;
        k_row<<<blocks, threads, 0, stream>>>(q, q_tar, pi, a_t, r_t, mu_t, done_t,
                                              adv, scr, T);
    }
    // K2a: chunk composition
    k_chunk<<<(nch + 255) / 256, 256, 0, stream>>>(scr, cab, T);
    // K2b: boundary scan (single block)
    k_scan<<<1, 1024, 0, stream>>>(cab, ybound, nch);
    // K2c: expand
    k_final<<<(nch + 255) / 256, 256, 0, stream>>>(scr, ybound, targets, T);
}

// Round 2
// 73.792 us; speedup vs baseline: 1.6085x; 1.6085x over previous
//
#include <hip/hip_runtime.h>

#define GAMMA 0.999f
#define LAMBD 0.7f
#define ALPHA 0.99f

constexpr int A_DIM = 64;
constexpr int CH    = 128;   // scan chunk length (T/CH = 2048 chunks)

__device__ __forceinline__ float pick4(const float4& v, int k) {
    float lo = (k & 1) ? v.y : v.x;
    float hi = (k & 1) ? v.w : v.z;
    return (k & 2) ? hi : lo;
}

// ---------------------------------------------------------------------------
// K1: 4 rows per wave. Lane layout: sub = lane>>4 (row within wave),
// li = lane&15 (16 lanes per row, float4 each -> 64 elements).
// Writes advantages (float4, coalesced) and scan coefficients
// scr[t] = {E, k, A, Bp}:  targets[t] = E + k*y_{t+1};  y_t = A + Bp*y_{t+1}.
// ---------------------------------------------------------------------------
__global__ void k_row(const float* __restrict__ q,
                      const float* __restrict__ q_tar,
                      const float* __restrict__ pi,
                      const int*   __restrict__ a_t,
                      const float* __restrict__ r_t,
                      const float* __restrict__ mu_t,
                      const int*   __restrict__ done_t,
                      float*  __restrict__ adv_out,   // T*A floats
                      float4* __restrict__ scr,       // T entries {E,k,A,Bp}
                      int T)
{
    int wave = (blockIdx.x * blockDim.x + threadIdx.x) >> 6;
    int lane = threadIdx.x & 63;
    int sub  = lane >> 4;
    int li   = lane & 15;
    int r    = wave * 4 + sub;
    if (r >= T) return;

    int base = r * A_DIM + li * 4;

    float4 pi4  = *(const float4*)&pi[base];
    float4 q4   = *(const float4*)&q[base];
    float4 pip4 = *(const float4*)&pi[base + A_DIM];
    float4 qp4  = *(const float4*)&q_tar[base + A_DIM];
    float4 mu4  = *(const float4*)&mu_t[base];

    float s0 = pi4.x*q4.x  + pi4.y*q4.y  + pi4.z*q4.z  + pi4.w*q4.w;   // -> v_t
    float s1 = pip4.x*qp4.x + pip4.y*qp4.y + pip4.z*qp4.z + pip4.w*qp4.w; // -> v_tp1
    #pragma unroll
    for (int off = 1; off < 16; off <<= 1) {
        s0 += __shfl_xor(s0, off);
        s1 += __shfl_xor(s1, off);
    }

    int   a  = a_t[r];
    float rr = r_t[r];
    float dn = (float)done_t[r];

    int src = (sub << 4) | (a >> 2);
    int ac  = a & 3;
    float q_t_a  = __shfl(pick4(q4,  ac), src);
    float pi_t_a = __shfl(pick4(pi4, ac), src);
    float mu_a   = __shfl(pick4(mu4, ac), src);

    float kmask = 1.0f - dn;
    float est = rr + kmask * (GAMMA * s1);
    float td  = est - q_t_a;
    float rho = pi_t_a / mu_a;
    float c   = LAMBD * fminf(fmaxf(rho, 0.0f), 1.0f);

    float Acoef = (LAMBD * GAMMA) * rho * td;
    float Bp    = kmask * (GAMMA * c);
    float E     = est + ALPHA * (q_t_a - s0);

    float4 adv4;
    adv4.x = (1.0f - ALPHA) * (q4.x - s0);
    adv4.y = (1.0f - ALPHA) * (q4.y - s0);
    adv4.z = (1.0f - ALPHA) * (q4.z - s0);
    adv4.w = (1.0f - ALPHA) * (q4.w - s0);
    *(float4*)&adv_out[base] = adv4;

    if (li == 0) scr[r] = make_float4(E, kmask, Acoef, Bp);
}

// ---------------------------------------------------------------------------
// K2a: one wave per 128-chunk. Lane l holds elements 2l, 2l+1.
// Wave-parallel inclusive SUFFIX scan of affine pairs (A,B), op:
//   comp(P,Q) (P outer, lower index): A = P.A + P.B*Q.A ; B = P.B*Q.B
// Stores per-element Sufx_t = comp(F_{t+1}..F_{last}) (identity for t=last)
// and the chunk total to cab[c].
// ---------------------------------------------------------------------------
__global__ void k_suffix(const float4* __restrict__ scr,
                         float2* __restrict__ sufx,
                         float2* __restrict__ cab, int T)
{
    int wave = (blockIdx.x * blockDim.x + threadIdx.x) >> 6;
    int lane = threadIdx.x & 63;
    int nch  = T / CH;
    if (wave >= nch) return;
    int base = wave * CH + lane * 2;

    float4 e0 = scr[base];       // {E,k,A,B}
    float4 e1 = scr[base + 1];

    // pair composite P_l = comp(F_{2l}, F_{2l+1})
    float Ai = e0.z + e0.w * e1.z;
    float Bi = e0.w * e1.w;

    // inclusive suffix scan: I_l = comp(P_l .. P_63)
    #pragma unroll
    for (int off = 1; off < 64; off <<= 1) {
        float An = __shfl_down(Ai, off);
        float Bn = __shfl_down(Bi, off);
        if (lane + off < 64) {
            Ai = Ai + Bi * An;
            Bi = Bi * Bn;
        }
    }
    // exclusive: X_l = I_{l+1}  (identity for lane 63)
    float Xa = __shfl_down(Ai, 1);
    float Xb = __shfl_down(Bi, 1);
    if (lane == 63) { Xa = 0.0f; Xb = 1.0f; }

    // Sufx_{2l+1} = X_l ; Sufx_{2l} = comp(F_{2l+1}, X_l)
    sufx[base + 1] = make_float2(Xa, Xb);
    sufx[base]     = make_float2(e1.z + e1.w * Xa, e1.w * Xb);

    if (lane == 0) cab[wave] = make_float2(Ai, Bi);
}

// ---------------------------------------------------------------------------
// K2b: single-block suffix scan over 2048 chunk pairs -> y at chunk starts.
// ---------------------------------------------------------------------------
__global__ void k_scan(const float2* __restrict__ cab,
                       float* __restrict__ ybound, int nch)
{
    __shared__ float sA[1024], sB[1024];
    int i = threadIdx.x;                 // handles chunks 2i, 2i+1
    float2 p0 = cab[2 * i];
    float2 p1 = cab[2 * i + 1];
    float Ai = p0.x + p0.y * p1.x;       // comp(p0, p1)
    float Bi = p0.y * p1.y;
    sA[i] = Ai; sB[i] = Bi;
    __syncthreads();
    for (int off = 1; off < 1024; off <<= 1) {
        float An = 0.0f, Bn = 1.0f;
        if (i + off < 1024) { An = sA[i + off]; Bn = sB[i + off]; }
        __syncthreads();
        Ai = Ai + Bi * An;
        Bi = Bi * Bn;
        sA[i] = Ai; sB[i] = Bi;
        __syncthreads();
    }
    ybound[2 * i] = Ai;
    float yNext = (i + 1 < 1024) ? sA[i + 1] : 0.0f;
    ybound[2 * i + 1] = p1.x + p1.y * yNext;
    if (i == 0) ybound[nch] = 0.0f;
}

// ---------------------------------------------------------------------------
// K2c: fully elementwise finalize.
//   y_{t+1} = Sufx_t(y_boundary[c+1]);  targets[t] = E_t + k_t * y_{t+1}
// ---------------------------------------------------------------------------
__global__ void k_final(const float4* __restrict__ scr,
                        const float2* __restrict__ sufx,
                        const float* __restrict__ ybound,
                        float* __restrict__ targets, int T)
{
    int t = blockIdx.x * blockDim.x + threadIdx.x;
    if (t >= T) return;
    float ye = ybound[(t >> 7) + 1];
    float2 sx = sufx[t];
    float4 v  = scr[t];
    float y_tp1 = sx.x + sx.y * ye;
    targets[t] = v.x + v.y * y_tp1;
}

extern "C" void kernel_launch(void* const* d_in, const int* in_sizes, int n_in,
                              void* d_out, int out_size, void* d_ws, size_t ws_size,
                              hipStream_t stream) {
    const float* q     = (const float*)d_in[0];
    const float* q_tar = (const float*)d_in[1];
    const float* pi    = (const float*)d_in[2];
    const int*   a_t   = (const int*)  d_in[3];
    const float* r_t   = (const float*)d_in[4];
    const float* mu_t  = (const float*)d_in[5];
    const int*   done_t= (const int*)  d_in[6];

    const int T   = in_sizes[3];         // 262144
    const int nch = T / CH;              // 2048

    float* targets = (float*)d_out;          // T floats
    float* adv     = (float*)d_out + T;      // T*A floats

    char* ws = (char*)d_ws;
    float4* scr    = (float4*)ws;                                  ws += (size_t)16 * T;
    float2* sufxb  = (float2*)ws;                                  ws += (size_t)8  * T;
    float2* cab    = (float2*)ws;                                  ws += (size_t)8  * nch;
    float*  ybound = (float*)ws;

    // K1: 4 rows per wave, 16 rows per 256-thread block
    {
        int blocks = T / 16;
        k_row<<<blocks, 256, 0, stream>>>(q, q_tar, pi, a_t, r_t, mu_t, done_t,
                                          adv, scr, T);
    }
    // K2a: wave-parallel per-chunk suffix composites (4 chunks per block)
    k_suffix<<<nch / 4, 256, 0, stream>>>(scr, sufxb, cab, T);
    // K2b: boundary scan (single block)
    k_scan<<<1, 1024, 0, stream>>>(cab, ybound, nch);
    // K2c: elementwise finalize
    k_final<<<(T + 255) / 256, 256, 0, stream>>>(scr, sufxb, ybound, targets, T);
}

// Round 3
// 73.390 us; speedup vs baseline: 1.6173x; 1.0055x over previous
//
#include <hip/hip_runtime.h>

#define GAMMA 0.999f
#define LAMBD 0.7f
#define ALPHA 0.99f

constexpr int A_DIM = 64;
constexpr int CH    = 128;   // rows per chunk == rows per block

__device__ __forceinline__ float pick4(const float4& v, int k) {
    float lo = (k & 1) ? v.y : v.x;
    float hi = (k & 1) ? v.w : v.z;
    return (k & 2) ? hi : lo;
}

struct RowRegs {
    float4 pi4, q4, pip4, qp4, mu4;
    int   a;
    float rr, dn;
};

__device__ __forceinline__ void row_load(const float* __restrict__ q,
                                         const float* __restrict__ q_tar,
                                         const float* __restrict__ pi,
                                         const float* __restrict__ mu_t,
                                         const int* __restrict__ a_t,
                                         const float* __restrict__ r_t,
                                         const int* __restrict__ done_t,
                                         int r, int li, RowRegs& R)
{
    int base = r * A_DIM + li * 4;
    R.pi4  = *(const float4*)&pi[base];
    R.q4   = *(const float4*)&q[base];
    R.pip4 = *(const float4*)&pi[base + A_DIM];
    R.qp4  = *(const float4*)&q_tar[base + A_DIM];
    R.mu4  = *(const float4*)&mu_t[base];
    R.a  = a_t[r];
    R.rr = r_t[r];
    R.dn = (float)done_t[r];
}

// Computes one row; all lanes write adv, li==0 lane stores {E,k,A,B} to LDS.
__device__ __forceinline__ void row_compute(const RowRegs& R, int sub, int li, int gbase,
                                            float* __restrict__ adv_out,
                                            float4* sEKAB, int lrow)
{
    float s0 = R.pi4.x*R.q4.x  + R.pi4.y*R.q4.y  + R.pi4.z*R.q4.z  + R.pi4.w*R.q4.w;
    float s1 = R.pip4.x*R.qp4.x + R.pip4.y*R.qp4.y + R.pip4.z*R.qp4.z + R.pip4.w*R.qp4.w;
    #pragma unroll
    for (int off = 1; off < 16; off <<= 1) {
        s0 += __shfl_xor(s0, off);
        s1 += __shfl_xor(s1, off);
    }
    int src = (sub << 4) | (R.a >> 2);
    int ac  = R.a & 3;
    float qa = __shfl(pick4(R.q4,  ac), src);
    float pa = __shfl(pick4(R.pi4, ac), src);
    float ma = __shfl(pick4(R.mu4, ac), src);

    float kmask = 1.0f - R.dn;
    float est = R.rr + kmask * (GAMMA * s1);
    float td  = est - qa;
    float rho = pa / ma;
    float c   = LAMBD * fminf(fmaxf(rho, 0.0f), 1.0f);

    float4 adv4;
    adv4.x = (1.0f - ALPHA) * (R.q4.x - s0);
    adv4.y = (1.0f - ALPHA) * (R.q4.y - s0);
    adv4.z = (1.0f - ALPHA) * (R.q4.z - s0);
    adv4.w = (1.0f - ALPHA) * (R.q4.w - s0);
    *(float4*)&adv_out[gbase] = adv4;

    if (li == 0)
        sEKAB[lrow] = make_float4(est + ALPHA * (qa - s0),   // E
                                  kmask,                      // k
                                  (LAMBD * GAMMA) * rho * td, // A
                                  kmask * (GAMMA * c));       // B
}

// ---------------------------------------------------------------------------
// K1: one block per 128-row chunk. 4 waves; wave w owns rows [w*32, w*32+32),
// processed 4-at-a-time (sub = lane>>4 picks row, li = lane&15 picks 4-col
// slice), two row-groups interleaved per loop step for ILP.
// After the rows: in-LDS affine suffix scan over the chunk, emitting per-row
//   comb[t] = {U, W} with targets[t] = U + W * ybound[chunk+1]
// and the chunk composite cab[chunk].
// ---------------------------------------------------------------------------
__global__ __launch_bounds__(256, 4)
void k_row(const float* __restrict__ q,
           const float* __restrict__ q_tar,
           const float* __restrict__ pi,
           const int*   __restrict__ a_t,
           const float* __restrict__ r_t,
           const float* __restrict__ mu_t,
           const int*   __restrict__ done_t,
           float*  __restrict__ adv_out,   // T*A floats
           float2* __restrict__ comb,      // T entries {U,W}
           float2* __restrict__ cab)       // nch entries
{
    __shared__ float4 sEKAB[CH];
    __shared__ float2 sUW[CH];

    int tid  = threadIdx.x;
    int wave = tid >> 6;       // 0..3
    int lane = tid & 63;
    int sub  = lane >> 4;
    int li   = lane & 15;
    int R0   = blockIdx.x * CH;

    #pragma unroll 2
    for (int i = 0; i < 8; i += 2) {
        int lrowA = wave * 32 + i * 4 + sub;
        int lrowB = lrowA + 4;
        int rA = R0 + lrowA;
        int rB = R0 + lrowB;
        RowRegs Ra, Rb;
        row_load(q, q_tar, pi, mu_t, a_t, r_t, done_t, rA, li, Ra);
        row_load(q, q_tar, pi, mu_t, a_t, r_t, done_t, rB, li, Rb);
        row_compute(Ra, sub, li, rA * A_DIM + li * 4, adv_out, sEKAB, lrowA);
        row_compute(Rb, sub, li, rB * A_DIM + li * 4, adv_out, sEKAB, lrowB);
    }
    __syncthreads();

    if (wave == 0) {
        // lane l holds rows 2l, 2l+1; suffix scan of pair composites.
        float4 e0 = sEKAB[2 * lane];
        float4 e1 = sEKAB[2 * lane + 1];
        float Ai = e0.z + e0.w * e1.z;   // comp(F_{2l}, F_{2l+1})
        float Bi = e0.w * e1.w;
        #pragma unroll
        for (int off = 1; off < 64; off <<= 1) {
            float An = __shfl_down(Ai, off);
            float Bn = __shfl_down(Bi, off);
            if (lane + off < 64) { Ai += Bi * An; Bi *= Bn; }
        }
        // exclusive suffix: X = comp(F_{2l+2}..F_end), identity at lane 63
        float Xa = __shfl_down(Ai, 1);
        float Xb = __shfl_down(Bi, 1);
        if (lane == 63) { Xa = 0.0f; Xb = 1.0f; }
        // row 2l+1: Sufx = X ;   row 2l: Sufx = comp(F_{2l+1}, X)
        sUW[2 * lane + 1] = make_float2(e1.x + e1.y * Xa, e1.y * Xb);
        float Sa = e1.z + e1.w * Xa;
        float Sb = e1.w * Xb;
        sUW[2 * lane]     = make_float2(e0.x + e0.y * Sa, e0.y * Sb);
        if (lane == 0) cab[blockIdx.x] = make_float2(Ai, Bi);
    }
    __syncthreads();
    if (tid < CH) comb[R0 + tid] = sUW[tid];
}

// ---------------------------------------------------------------------------
// K2: single-block suffix scan over 2048 chunk composites -> y at chunk starts
// ---------------------------------------------------------------------------
__global__ void k_scan(const float2* __restrict__ cab,
                       float* __restrict__ ybound, int nch)
{
    __shared__ float sA[1024], sB[1024];
    int i = threadIdx.x;                 // handles chunks 2i, 2i+1
    float2 p0 = cab[2 * i];
    float2 p1 = cab[2 * i + 1];
    float Ai = p0.x + p0.y * p1.x;       // comp(p0, p1)
    float Bi = p0.y * p1.y;
    sA[i] = Ai; sB[i] = Bi;
    __syncthreads();
    for (int off = 1; off < 1024; off <<= 1) {
        float An = 0.0f, Bn = 1.0f;
        if (i + off < 1024) { An = sA[i + off]; Bn = sB[i + off]; }
        __syncthreads();
        Ai = Ai + Bi * An;
        Bi = Bi * Bn;
        sA[i] = Ai; sB[i] = Bi;
        __syncthreads();
    }
    ybound[2 * i] = Ai;
    float yNext = (i + 1 < 1024) ? sA[i + 1] : 0.0f;
    ybound[2 * i + 1] = p1.x + p1.y * yNext;
    if (i == 0) ybound[nch] = 0.0f;
}

// ---------------------------------------------------------------------------
// K3: trivial elementwise finalize: targets[t] = U + W * ybound[c+1]
// ---------------------------------------------------------------------------
__global__ void k_final(const float2* __restrict__ comb,
                        const float* __restrict__ ybound,
                        float* __restrict__ targets, int T)
{
    int t = blockIdx.x * blockDim.x + threadIdx.x;
    if (t >= T) return;
    float ye = ybound[(t >> 7) + 1];
    float2 uw = comb[t];
    targets[t] = uw.x + uw.y * ye;
}

extern "C" void kernel_launch(void* const* d_in, const int* in_sizes, int n_in,
                              void* d_out, int out_size, void* d_ws, size_t ws_size,
                              hipStream_t stream) {
    const float* q     = (const float*)d_in[0];
    const float* q_tar = (const float*)d_in[1];
    const float* pi    = (const float*)d_in[2];
    const int*   a_t   = (const int*)  d_in[3];
    const float* r_t   = (const float*)d_in[4];
    const float* mu_t  = (const float*)d_in[5];
    const int*   done_t= (const int*)  d_in[6];

    const int T   = in_sizes[3];         // 262144
    const int nch = T / CH;              // 2048

    float* targets = (float*)d_out;          // T floats
    float* adv     = (float*)d_out + T;      // T*A floats

    char* ws = (char*)d_ws;
    float2* comb   = (float2*)ws;            ws += (size_t)8 * T;
    float2* cab    = (float2*)ws;            ws += (size_t)8 * nch;
    float*  ybound = (float*)ws;

    // K1: one block per 128-row chunk (fused row compute + chunk suffix scan)
    k_row<<<nch, 256, 0, stream>>>(q, q_tar, pi, a_t, r_t, mu_t, done_t,
                                   adv, comb, cab);
    // K2: boundary scan (single block)
    k_scan<<<1, 1024, 0, stream>>>(cab, ybound, nch);
    // K3: elementwise finalize
    k_final<<<(T + 255) / 256, 256, 0, stream>>>(comb, ybound, targets, T);
}

// Round 5
// 66.128 us; speedup vs baseline: 1.7949x; 1.1098x over previous
//
#include <hip/hip_runtime.h>

#define GAMMA 0.999f
#define LAMBD 0.7f
#define ALPHA 0.99f

constexpr int A_DIM = 64;
constexpr int CH    = 256;   // rows per block; nch = T/CH = 1024

// ---------------------------------------------------------------------------
// K1: one block per 256-row chunk.
//  Phase A (tid = local row): stage a_t/r_t/done, and gather q/pi/mu at the
//           action index directly (4B loads; q/pi rows are re-read by phase B
//           so only mu's touched lines add HBM traffic).
//  Phase B: dot products. Wave w owns rows [w*64,(w+1)*64), 4 rows per wave
//           step (sub=lane>>4, li=lane&15, float4 per lane), 2 steps
//           interleaved for ILP. Butterfly-reduce 16 lanes -> v_t, v_tp1;
//           write advantages (float4, coalesced).
//  Phase C (tid = local row): build affine F=(A,B), E, k; 256-entry
//           Hillis-Steele suffix scan in LDS; emit comb[t]={U,W} with
//           targets[t] = U + W*ye(chunk), and cab[chunk] composite.
// ---------------------------------------------------------------------------
__global__ __launch_bounds__(256, 6)
void k_main(const float* __restrict__ q, const float* __restrict__ q_tar,
            const float* __restrict__ pi, const int* __restrict__ a_t,
            const float* __restrict__ r_t, const float* __restrict__ mu_t,
            const int* __restrict__ done_t,
            float* __restrict__ adv_out,
            float2* __restrict__ comb, float2* __restrict__ cab)
{
    __shared__ float sQa[CH], sRho[CH], sKm[CH], sRt[CH];
    __shared__ float sV[CH], sVp[CH];
    __shared__ float sA[CH], sB[CH];

    const int tid  = threadIdx.x;
    const int wave = tid >> 6, lane = tid & 63;
    const int sub  = lane >> 4, li = lane & 15;
    const int R0   = blockIdx.x * CH;

    // ---- phase A: per-thread staging + action-index gathers
    {
        int r = R0 + tid;
        int a = a_t[r];
        sRt[tid] = r_t[r];
        sKm[tid] = 1.0f - (float)done_t[r];
        float qa = q[r * A_DIM + a];
        float pa = pi[r * A_DIM + a];
        float ma = mu_t[r * A_DIM + a];
        sQa[tid]  = qa;
        sRho[tid] = pa / ma;
    }

    // ---- phase B: dots + advantages (no sync needed before; disjoint LDS)
    #pragma unroll 2
    for (int i = 0; i < 8; ++i) {
        int lrowA = wave * 64 + i * 8 + sub;
        int lrowB = lrowA + 4;
        int gA = (R0 + lrowA) * A_DIM + li * 4;
        int gB = (R0 + lrowB) * A_DIM + li * 4;

        float4 piA  = *(const float4*)&pi[gA];
        float4 qA   = *(const float4*)&q[gA];
        float4 pipA = *(const float4*)&pi[gA + A_DIM];
        float4 qpA  = *(const float4*)&q_tar[gA + A_DIM];
        float4 piB  = *(const float4*)&pi[gB];
        float4 qB   = *(const float4*)&q[gB];
        float4 pipB = *(const float4*)&pi[gB + A_DIM];
        float4 qpB  = *(const float4*)&q_tar[gB + A_DIM];

        float s0A = piA.x*qA.x + piA.y*qA.y + piA.z*qA.z + piA.w*qA.w;
        float s1A = pipA.x*qpA.x + pipA.y*qpA.y + pipA.z*qpA.z + pipA.w*qpA.w;
        float s0B = piB.x*qB.x + piB.y*qB.y + piB.z*qB.z + piB.w*qB.w;
        float s1B = pipB.x*qpB.x + pipB.y*qpB.y + pipB.z*qpB.z + pipB.w*qpB.w;
        #pragma unroll
        for (int off = 1; off < 16; off <<= 1) {
            s0A += __shfl_xor(s0A, off);
            s1A += __shfl_xor(s1A, off);
            s0B += __shfl_xor(s0B, off);
            s1B += __shfl_xor(s1B, off);
        }

        float4 advA, advB;
        advA.x = (1.0f - ALPHA) * (qA.x - s0A);
        advA.y = (1.0f - ALPHA) * (qA.y - s0A);
        advA.z = (1.0f - ALPHA) * (qA.z - s0A);
        advA.w = (1.0f - ALPHA) * (qA.w - s0A);
        advB.x = (1.0f - ALPHA) * (qB.x - s0B);
        advB.y = (1.0f - ALPHA) * (qB.y - s0B);
        advB.z = (1.0f - ALPHA) * (qB.z - s0B);
        advB.w = (1.0f - ALPHA) * (qB.w - s0B);
        *(float4*)&adv_out[gA] = advA;
        *(float4*)&adv_out[gB] = advB;

        if (li == 0) {
            sV[lrowA]  = s0A;  sVp[lrowA] = s1A;
            sV[lrowB]  = s0B;  sVp[lrowB] = s1B;
        }
    }
    __syncthreads();

    // ---- phase C: per-thread coefficients + block suffix scan
    float s0    = sV[tid],  s1 = sVp[tid];
    float kmask = sKm[tid];
    float qa    = sQa[tid];
    float rho   = sRho[tid];
    float est = sRt[tid] + kmask * (GAMMA * s1);
    float td  = est - qa;
    float c   = LAMBD * fminf(fmaxf(rho, 0.0f), 1.0f);
    float Fa  = (LAMBD * GAMMA) * rho * td;    // y_t = Fa + Fb * y_{t+1}
    float Fb  = kmask * (GAMMA * c);
    float E   = est + ALPHA * (qa - s0);       // targets = E + kmask * y_{t+1}

    float Ai = Fa, Bi = Fb;                    // inclusive suffix scan
    sA[tid] = Ai; sB[tid] = Bi;
    __syncthreads();
    #pragma unroll
    for (int off = 1; off < CH; off <<= 1) {
        float An = 0.0f, Bn = 1.0f;
        if (tid + off < CH) { An = sA[tid + off]; Bn = sB[tid + off]; }
        __syncthreads();
        Ai += Bi * An; Bi *= Bn;
        sA[tid] = Ai; sB[tid] = Bi;
        __syncthreads();
    }
    float Xa = 0.0f, Xb = 1.0f;                // exclusive: suffix from tid+1
    if (tid + 1 < CH) { Xa = sA[tid + 1]; Xb = sB[tid + 1]; }
    comb[R0 + tid] = make_float2(E + kmask * Xa, kmask * Xb);
    if (tid == 0) cab[blockIdx.x] = make_float2(Ai, Bi);
}

// ---------------------------------------------------------------------------
// K2: each block redundantly suffix-scans the nch=1024 chunk composites
// (8 KB, L2-hot), extracts ye = y at its chunk end, finalizes its 256 rows.
// ---------------------------------------------------------------------------
__global__ __launch_bounds__(256, 8)
void k_fin(const float2* __restrict__ comb, const float2* __restrict__ cab,
           float* __restrict__ targets, int nch)
{
    __shared__ float sA[256], sB[256];
    __shared__ float sYe;
    const int tid = threadIdx.x, bid = blockIdx.x;

    // fold 4 consecutive chunks per thread: supers = nch/4 = 256
    const float4* cab4 = (const float4*)cab;
    float4 u0 = cab4[2 * tid];
    float4 u1 = cab4[2 * tid + 1];
    float A = u0.x, B = u0.y;
    A += B * u0.z; B *= u0.w;
    A += B * u1.x; B *= u1.y;
    A += B * u1.z; B *= u1.w;
    sA[tid] = A; sB[tid] = B;
    __syncthreads();
    #pragma unroll
    for (int off = 1; off < 256; off <<= 1) {
        float An = 0.0f, Bn = 1.0f;
        if (tid + off < 256) { An = sA[tid + off]; Bn = sB[tid + off]; }
        __syncthreads();
        A += B * An; B *= Bn;
        sA[tid] = A; sB[tid] = B;
        __syncthreads();
    }
    if (tid == 0) {
        int c1 = bid + 1;                      // need suffix over chunks c1..nch-1
        int jq = c1 >> 2, rq = c1 & 3;
        float ye;
        if (rq == 0) {
            ye = (jq < 256) ? sA[jq] : 0.0f;
        } else {
            float Aa = (jq + 1 < 256) ? sA[jq + 1] : 0.0f;
            float Bb = (jq + 1 < 256) ? sB[jq + 1] : 1.0f;
            for (int k2 = 4 * jq + 3; k2 >= c1; --k2) {
                float2 cv = cab[k2];
                Aa = cv.x + cv.y * Aa;
                Bb = cv.y * Bb;
            }
            ye = Aa;
        }
        sYe = ye;
    }
    __syncthreads();

    float2 uw = comb[bid * CH + tid];
    targets[bid * CH + tid] = uw.x + uw.y * sYe;
}

extern "C" void kernel_launch(void* const* d_in, const int* in_sizes, int n_in,
                              void* d_out, int out_size, void* d_ws, size_t ws_size,
                              hipStream_t stream) {
    const float* q      = (const float*)d_in[0];
    const float* q_tar  = (const float*)d_in[1];
    const float* pi     = (const float*)d_in[2];
    const int*   a_t    = (const int*)  d_in[3];
    const float* r_t    = (const float*)d_in[4];
    const float* mu_t   = (const float*)d_in[5];
    const int*   done_t = (const int*)  d_in[6];

    const int T   = in_sizes[3];         // 262144
    const int nch = T / CH;              // 1024

    float* targets = (float*)d_out;          // T floats
    float* adv     = (float*)d_out + T;      // T*A floats

    char* ws = (char*)d_ws;
    float2* comb = (float2*)ws;              ws += (size_t)8 * T;
    float2* cab  = (float2*)ws;

    k_main<<<nch, 256, 0, stream>>>(q, q_tar, pi, a_t, r_t, mu_t, done_t,
                                    adv, comb, cab);
    k_fin<<<nch, 256, 0, stream>>>(comb, cab, targets, nch);
}